// Round 5
// baseline (2114.492 us; speedup 1.0000x reference)
//
#include <hip/hip_runtime.h>
#include <stdint.h>

#define N_NODES  100000
#define N_EDGES  1600000
#define E_TOT    1700000   // + self loops
#define F_DIM    192
#define IN_DIM   256
#define NGRAPH   64
#define NCLS     10
#define N_UNITS_ATTN 300000          // 100000 dst * 3 heads
#define NODE_ELEMS   19200000LL      // N_NODES * F_DIM

// output element offsets (dtype-independent)
#define LOGITS_OFF 0LL
#define PRE_OFF    640LL
#define PP_OFF     19200640LL
#define FC_OFF     19212928LL

typedef __attribute__((ext_vector_type(8))) short short8v;   // 16B raw load
typedef __attribute__((ext_vector_type(8))) __bf16 bf16x8;   // MFMA A/B operand (V8y)
typedef __attribute__((ext_vector_type(4))) float f32x4;

__device__ __forceinline__ float bf2f(unsigned short u) {
  union { unsigned int i; float f; } c; c.i = ((unsigned int)u) << 16; return c.f;
}
__device__ __forceinline__ unsigned short f2bf(float f) {
  union { float f; unsigned int i; } c; c.f = f;
  unsigned int r = (c.i + 0x7FFFu + ((c.i >> 16) & 1u)) >> 16;
  return (unsigned short)r;
}
// 16B load of 8 bf16 (stored as ushort) -> properly-typed MFMA fragment
__device__ __forceinline__ bf16x8 ld_frag(const unsigned short* p) {
  return __builtin_bit_cast(bf16x8, *(const short8v*)p);
}
// dtype-aware float load/store (isbf: 1 = bf16 buffer, 0 = fp32 buffer)
__device__ __forceinline__ float ldf(const void* p, int isbf, long long i) {
  return isbf ? bf2f(((const unsigned short*)p)[i]) : ((const float*)p)[i];
}
__device__ __forceinline__ void stf(void* p, int isbf, long long i, float v) {
  if (isbf) ((unsigned short*)p)[i] = f2bf(v);
  else      ((float*)p)[i] = v;
}
// vectorized 4-channel load/store (element index i must be a multiple of 4)
__device__ __forceinline__ f32x4 ld4(const void* p, int isbf, long long i) {
  if (isbf) {
    ushort4 u = *(const ushort4*)((const unsigned short*)p + i);
    return (f32x4){bf2f(u.x), bf2f(u.y), bf2f(u.z), bf2f(u.w)};
  }
  const float4 v = *(const float4*)((const float*)p + i);
  return (f32x4){v.x, v.y, v.z, v.w};
}
__device__ __forceinline__ void st4(void* p, int isbf, long long i, f32x4 v) {
  if (isbf) {
    ushort4 u;
    u.x = f2bf(v.x); u.y = f2bf(v.y); u.z = f2bf(v.z); u.w = f2bf(v.w);
    *(ushort4*)((unsigned short*)p + i) = u;
  } else {
    float4 o; o.x = v.x; o.y = v.y; o.z = v.z; o.w = v.w;
    *(float4*)((float*)p + i) = o;
  }
}
// int32 buffer, or little-endian int64 (read low word)
__device__ __forceinline__ int ld_idx(const int* __restrict__ p, int is64, long long i) {
  return is64 ? p[i << 1] : p[(size_t)i];
}

// restore the template symbol (harness may reference it); launched as a no-op
__global__ void AmazonNet_36704790511894_kernel() {}

// ---------------------------------------------------------------------------
// dtype probe. flags[0]=ei is int64, flags[1]=batch is int64, flags[2]=floats
// are bf16.
// ---------------------------------------------------------------------------
__global__ __launch_bounds__(256) void detect_k(const int* __restrict__ ei,
                                                const int* __restrict__ bat,
                                                const unsigned short* __restrict__ x,
                                                int* __restrict__ flags) {
  __shared__ int red[3];
  int t = threadIdx.x;
  if (t < 3) red[t] = 0;
  __syncthreads();
  int o1 = 0, o2 = 0, c3 = 0;
  for (int k = t; k < N_EDGES; k += 256 * 100)   // high words if int64
    o1 |= ei[2 * k + 1];
  for (int k = t; k < 50000; k += 256)           // covers tail (batch sorted)
    o2 |= bat[2 * k + 1];
  for (int k = t; k < 4096; k += 256) {
    unsigned short u = x[2 * k];
    c3 += (((u >> 7) & 0xFF) == 0xFF);
  }
  atomicOr(&red[0], o1);
  atomicOr(&red[1], o2);
  atomicAdd(&red[2], c3);
  __syncthreads();
  if (t == 0) {
    flags[0] = (red[0] == 0);
    flags[1] = (red[1] == 0);
    flags[2] = (red[2] < 4);   // <4 NaN-pattern hits -> genuine bf16
  }
}

// ---------------------------------------------------------------------------
// zero deg|pool_sum|cnt + diagnostic sentinel in logits
// ---------------------------------------------------------------------------
#define ZWORDS (N_NODES + NGRAPH * F_DIM + NGRAPH)   // 112352
__global__ __launch_bounds__(256) void zero_k(int* __restrict__ zbase,
                                              void* __restrict__ dout,
                                              const int* __restrict__ flags) {
  int i = blockIdx.x * 256 + threadIdx.x;
  if (i < ZWORDS) zbase[i] = 0;
  if (i < NGRAPH * NCLS) stf(dout, flags[2], LOGITS_OFF + i, 0.001f);
}

// ---------------------------------------------------------------------------
// W split+transpose: W [256][192] (fp32 or bf16) -> wt[4][192][256] bf16:
//   0 = Wl_hi, 1 = Wl_lo, 2 = Wr_hi, 3 = Wr_lo   (hi = bf16 RNE, lo = bf16(v-hi))
// ---------------------------------------------------------------------------
#define WT_N 49152   // 192*256
__global__ __launch_bounds__(256) void wsplit_k(const void* __restrict__ Wl,
                                                const void* __restrict__ Wr,
                                                const int* __restrict__ flags,
                                                unsigned short* __restrict__ wt) {
  int fbf = flags[2];
  int i = blockIdx.x * 256 + threadIdx.x;   // over 49152
  if (i >= WT_N) return;
  int k = i / F_DIM, n = i - k * F_DIM;     // i = k*192 + n
  long long o = (long long)n * IN_DIM + k;  // transposed: [n][k]
  float vl = ldf(Wl, fbf, i);
  float vr = ldf(Wr, fbf, i);
  unsigned short h = f2bf(vl);
  wt[o]            = h;
  wt[WT_N + o]     = f2bf(vl - bf2f(h));
  h = f2bf(vr);
  wt[2 * WT_N + o] = h;
  wt[3 * WT_N + o] = f2bf(vr - bf2f(h));
}

// ---------------------------------------------------------------------------
// Split-bf16 MFMA GEMM: C = X@W + b for BOTH Wl and Wr in one block.
// Block = 256 thr / 4 waves, BM=64 rows; each wave owns 16 rows x full 192 cols.
// X tile staged hi/lo bf16 in LDS with XOR swizzle to break the stride-512B
// bank conflict on ds_read_b128. B-fragments read from wt (L2-resident, 384 KB).
// 3-term Markidis: acc += Ah*Bh + Al*Bh + Ah*Bl  (error ~2^-17, ok vs fp32 ref).
// xl -> FC_OFF, xr -> PRE_OFF (same placement the attention pass expects).
// ---------------------------------------------------------------------------
#define BM 64
#define MBLK ((N_NODES + BM - 1) / BM)   // 1563
__global__ __launch_bounds__(256) void gemm_mfma(const void* __restrict__ x,
                                                 const unsigned short* __restrict__ wt,
                                                 const void* __restrict__ bl,
                                                 const void* __restrict__ br,
                                                 void* __restrict__ dout,
                                                 const int* __restrict__ flags) {
  __shared__ __align__(16) unsigned short xsh[BM * IN_DIM];
  __shared__ __align__(16) unsigned short xsl[BM * IN_DIM];
  int fbf = flags[2];
  int t = threadIdx.x;
  int lane = t & 63, wv = t >> 6;
  int m0 = blockIdx.x * BM;

  // ---- stage X tile as bf16 hi/lo, swizzled ----
  // 16384 elems, each thread converts 16 chunks of 4 consecutive elements
#pragma unroll
  for (int it = 0; it < 16; ++it) {
    int idx = (it * 256 + t) * 4;        // tile element index = row*256 + k
    int row = idx >> 8;
    int grow = m0 + row;
    ushort4 h4, l4;
    float v0 = 0.f, v1 = 0.f, v2 = 0.f, v3 = 0.f;
    if (grow < N_NODES) {
      long long g = (long long)grow * IN_DIM + (idx & 255);
      v0 = ldf(x, fbf, g);
      v1 = ldf(x, fbf, g + 1);
      v2 = ldf(x, fbf, g + 2);
      v3 = ldf(x, fbf, g + 3);
    }
    h4.x = f2bf(v0); l4.x = f2bf(v0 - bf2f(h4.x));
    h4.y = f2bf(v1); l4.y = f2bf(v1 - bf2f(h4.y));
    h4.z = f2bf(v2); l4.z = f2bf(v2 - bf2f(h4.z));
    h4.w = f2bf(v3); l4.w = f2bf(v3 - bf2f(h4.w));
    int sidx = idx ^ ((row & 7) << 3);   // element-index swizzle (multiple of 8)
    *(ushort4*)&xsh[sidx] = h4;
    *(ushort4*)&xsl[sidx] = l4;
  }
  __syncthreads();

  // ---- MFMA main loop ----
  f32x4 accL[12], accR[12];
#pragma unroll
  for (int n = 0; n < 12; ++n) {
    accL[n] = (f32x4){0.f, 0.f, 0.f, 0.f};
    accR[n] = (f32x4){0.f, 0.f, 0.f, 0.f};
  }
  int r = lane & 15, kq = lane >> 4;
  int arow = wv * 16 + r;
  const unsigned short* wlh = wt;
  const unsigned short* wll = wt + WT_N;
  const unsigned short* wrh = wt + 2 * WT_N;
  const unsigned short* wrl = wt + 3 * WT_N;

  for (int ks = 0; ks < 8; ++ks) {
    int k0 = ks * 32 + kq * 8;
    int sidx = (arow * IN_DIM + k0) ^ ((arow & 7) << 3);
    bf16x8 ah = ld_frag(&xsh[sidx]);
    bf16x8 al = ld_frag(&xsl[sidx]);
#pragma unroll
    for (int n = 0; n < 12; ++n) {
      long long wo = (long long)(n * 16 + r) * IN_DIM + k0;
      bf16x8 blh = ld_frag(&wlh[wo]);
      bf16x8 bll = ld_frag(&wll[wo]);
      bf16x8 brh = ld_frag(&wrh[wo]);
      bf16x8 brl = ld_frag(&wrl[wo]);
      accL[n] = __builtin_amdgcn_mfma_f32_16x16x32_bf16(ah, blh, accL[n], 0, 0, 0);
      accL[n] = __builtin_amdgcn_mfma_f32_16x16x32_bf16(al, blh, accL[n], 0, 0, 0);
      accL[n] = __builtin_amdgcn_mfma_f32_16x16x32_bf16(ah, bll, accL[n], 0, 0, 0);
      accR[n] = __builtin_amdgcn_mfma_f32_16x16x32_bf16(ah, brh, accR[n], 0, 0, 0);
      accR[n] = __builtin_amdgcn_mfma_f32_16x16x32_bf16(al, brh, accR[n], 0, 0, 0);
      accR[n] = __builtin_amdgcn_mfma_f32_16x16x32_bf16(ah, brl, accR[n], 0, 0, 0);
    }
  }

  // ---- epilogue: C/D layout col=lane&15, row=(lane>>4)*4+reg (m89-verified) ----
  int orow0 = m0 + wv * 16 + (lane >> 4) * 4;
  int colr = lane & 15;
#pragma unroll
  for (int n = 0; n < 12; ++n) {
    int c = n * 16 + colr;
    float bLv = ldf(bl, fbf, c);
    float bRv = ldf(br, fbf, c);
#pragma unroll
    for (int rr = 0; rr < 4; ++rr) {
      int grow = orow0 + rr;
      if (grow < N_NODES) {
        stf(dout, fbf, FC_OFF  + (long long)grow * F_DIM + c, accL[n][rr] + bLv);
        stf(dout, fbf, PRE_OFF + (long long)grow * F_DIM + c, accR[n][rr] + bRv);
      }
    }
  }
}

// ---------------------------------------------------------------------------
// CSR build by destination
// ---------------------------------------------------------------------------
__global__ __launch_bounds__(256) void hist_k(const int* __restrict__ ei,
                                              const int* __restrict__ batch,
                                              const int* __restrict__ flags,
                                              int* __restrict__ deg,
                                              int* __restrict__ cnt) {
  int is64e = flags[0], is64b = flags[1];
  int e = blockIdx.x * 256 + threadIdx.x;
  if (e < E_TOT) {
    int s, d;
    if (e < N_EDGES) {
      s = ld_idx(ei, is64e, e);
      d = ld_idx(ei, is64e, (long long)N_EDGES + e);
    } else s = d = e - N_EDGES;
    if ((unsigned)d < (unsigned)N_NODES && (unsigned)s < (unsigned)N_NODES)
      atomicAdd(&deg[d], 1);
  }
  if (e < N_NODES) {
    int g = ld_idx(batch, is64b, e);
    if ((unsigned)g < (unsigned)NGRAPH) atomicAdd(&cnt[g], 1);
  }
}

__global__ __launch_bounds__(256) void scan_a(const int* __restrict__ deg, int* __restrict__ csum) {
  __shared__ int red[256];
  int b = blockIdx.x, t = threadIdx.x;
  int base = b * 1024 + t * 4;
  int s = 0;
#pragma unroll
  for (int k = 0; k < 4; ++k) { int idx = base + k; if (idx < N_NODES) s += deg[idx]; }
  red[t] = s;
  __syncthreads();
  for (int off = 128; off; off >>= 1) {
    if (t < off) red[t] += red[t + off];
    __syncthreads();
  }
  if (t == 0) csum[b] = red[0];
}

__global__ void scan_b(int* csum, int* row_ptr, int nblk) {
  if (threadIdx.x == 0 && blockIdx.x == 0) {
    int run = 0;
    for (int b = 0; b < nblk; ++b) { int s = csum[b]; csum[b] = run; run += s; }
    row_ptr[N_NODES] = run;
  }
}

__global__ __launch_bounds__(256) void scan_c(const int* __restrict__ deg,
                                              const int* __restrict__ csum,
                                              int* __restrict__ row_ptr,
                                              int* __restrict__ cursor) {
  __shared__ int tsum[256];
  int b = blockIdx.x, t = threadIdx.x;
  int base = b * 1024 + t * 4;
  int v[4];
  int s = 0;
#pragma unroll
  for (int k = 0; k < 4; ++k) {
    int idx = base + k;
    v[k] = (idx < N_NODES) ? deg[idx] : 0;
    s += v[k];
  }
  tsum[t] = s;
  __syncthreads();
  for (int off = 1; off < 256; off <<= 1) {
    int x = (t >= off) ? tsum[t - off] : 0;
    __syncthreads();
    tsum[t] += x;
    __syncthreads();
  }
  int run = csum[b] + tsum[t] - s;
#pragma unroll
  for (int k = 0; k < 4; ++k) {
    int idx = base + k;
    if (idx < N_NODES) { row_ptr[idx] = run; cursor[idx] = run; }
    run += v[k];
  }
}

__global__ __launch_bounds__(256) void fill_k(const int* __restrict__ ei,
                                              const int* __restrict__ flags,
                                              int* __restrict__ cursor,
                                              int* __restrict__ edge_src) {
  int is64e = flags[0];
  int e = blockIdx.x * 256 + threadIdx.x;
  if (e >= E_TOT) return;
  int s, d;
  if (e < N_EDGES) {
    s = ld_idx(ei, is64e, e);
    d = ld_idx(ei, is64e, (long long)N_EDGES + e);
  } else s = d = e - N_EDGES;
  if ((unsigned)d < (unsigned)N_NODES && (unsigned)s < (unsigned)N_NODES) {
    int pos = atomicAdd(&cursor[d], 1);
    edge_src[pos] = s;
  }
}

// ---------------------------------------------------------------------------
// Pass 1 (restructured): one 16-lane unit per (dst, head); 4 units per wave.
// Each lane owns 4 channels (float4). Units 0-2 of a wave are the 3 heads of
// the same dst -> shared edge list, gathers coalesce to one contiguous row.
// 4 independent dep-chains per wave hide gather latency; reduce is 4 shfl.
// xl at FC_OFF (read-only), xr at PRE_OFF; result overwrites PRE_OFF slot.
// ---------------------------------------------------------------------------
__global__ __launch_bounds__(256) void attn1_k(void* __restrict__ dout,
                                               const void* __restrict__ att,
                                               const void* __restrict__ bias,
                                               const int* __restrict__ row_ptr,
                                               const int* __restrict__ edge_src,
                                               const int* __restrict__ flags) {
  int fbf = flags[2];
  int lane = threadIdx.x & 63;
  int wid = (blockIdx.x * 256 + threadIdx.x) >> 6;   // global wave id
  int gu = wid * 4 + (lane >> 4);                    // unit id = dst*3 + head
  if (gu >= N_UNITS_ATTN) return;                    // grid exact: never taken
  int i = gu / 3;
  int h = gu - i * 3;
  int sl = lane & 15;
  int c0 = h * 64 + sl * 4;                          // 4 channels per lane

  f32x4 xr4 = ld4(dout, fbf, PRE_OFF + (long long)i * F_DIM + c0);
  f32x4 at4 = ld4(att, fbf, c0);
  int start = row_ptr[i];
  int deg   = row_ptr[i + 1] - start;

  // wave-wide max degree (deg uniform within each 16-lane unit)
  int dm = deg;
  dm = max(dm, __shfl_xor(dm, 16));
  dm = max(dm, __shfl_xor(dm, 32));

  float m = -1e30f, s = 0.f;
  f32x4 o = (f32x4){0.f, 0.f, 0.f, 0.f};
  f32x4 xlc = (f32x4){0.f, 0.f, 0.f, 0.f};
  if (deg > 0)
    xlc = ld4(dout, fbf, FC_OFF + (long long)edge_src[start] * F_DIM + c0);

  for (int e = 0; e < dm; ++e) {
    f32x4 xln = (f32x4){0.f, 0.f, 0.f, 0.f};
    if (e + 1 < deg)
      xln = ld4(dout, fbf, FC_OFF + (long long)edge_src[start + e + 1] * F_DIM + c0);
    if (e < deg) {
      f32x4 tt = xlc + xr4;
      tt.x = tt.x > 0.f ? tt.x : 0.2f * tt.x;        // GATv2 leaky_relu, slope 0.2
      tt.y = tt.y > 0.f ? tt.y : 0.2f * tt.y;
      tt.z = tt.z > 0.f ? tt.z : 0.2f * tt.z;
      tt.w = tt.w > 0.f ? tt.w : 0.2f * tt.w;
      float pp = tt.x * at4.x + tt.y * at4.y + tt.z * at4.z + tt.w * at4.w;
#pragma unroll
      for (int d = 1; d < 16; d <<= 1) pp += __shfl_xor(pp, d);  // unit-level sum
      float mn = fmaxf(m, pp);
      float cf = __expf(m - mn);
      float w  = __expf(pp - mn);
      s = s * cf + w;
      o.x = o.x * cf + w * xlc.x;
      o.y = o.y * cf + w * xlc.y;
      o.z = o.z * cf + w * xlc.z;
      o.w = o.w * cf + w * xlc.w;
      m = mn;
    }
    xlc = xln;
  }
  float inv = (s > 0.f) ? 1.f / s : 0.f;
  f32x4 b4 = ld4(bias, fbf, c0);
  f32x4 val;
  val.x = o.x * inv + b4.x;
  val.y = o.y * inv + b4.y;
  val.z = o.z * inv + b4.z;
  val.w = o.w * inv + b4.w;
  st4(dout, fbf, PRE_OFF + (long long)i * F_DIM + c0, val);
}

// ---------------------------------------------------------------------------
// Pass 2 (vectorized x4): fc (at PRE_OFF) -> out_fc; leaky_relu -> out_pre;
// pool atomics. 192 % 4 == 0 so a 4-chunk never crosses a row boundary.
// ---------------------------------------------------------------------------
__global__ __launch_bounds__(256) void post_k(void* __restrict__ dout,
                                              const int* __restrict__ batch,
                                              const int* __restrict__ flags,
                                              float* __restrict__ pool_sum) {
  int fbf = flags[2], is64b = flags[1];
  long long idx = ((long long)blockIdx.x * 256 + threadIdx.x) * 4;
  if (idx >= NODE_ELEMS) return;
  int i = (int)(idx / F_DIM);
  int c = (int)(idx - (long long)i * F_DIM);
  f32x4 fc = ld4(dout, fbf, PRE_OFF + idx);
  st4(dout, fbf, FC_OFF + idx, fc);
  f32x4 pre;
  pre.x = fc.x > 0.f ? fc.x : 0.01f * fc.x;        // F.leaky_relu default slope
  pre.y = fc.y > 0.f ? fc.y : 0.01f * fc.y;
  pre.z = fc.z > 0.f ? fc.z : 0.01f * fc.z;
  pre.w = fc.w > 0.f ? fc.w : 0.01f * fc.w;
  st4(dout, fbf, PRE_OFF + idx, pre);
  int g = ld_idx(batch, is64b, i);
  if ((unsigned)g < (unsigned)NGRAPH) {
    float* ps = &pool_sum[g * F_DIM + c];
    atomicAdd(&ps[0], pre.x);
    atomicAdd(&ps[1], pre.y);
    atomicAdd(&ps[2], pre.z);
    atomicAdd(&ps[3], pre.w);
  }
}

// ---------------------------------------------------------------------------
__global__ __launch_bounds__(192) void final_k(const float* __restrict__ pool_sum,
                                               const int* __restrict__ cnt,
                                               const void* __restrict__ Wc,
                                               const void* __restrict__ bc,
                                               void* __restrict__ dout,
                                               const int* __restrict__ flags) {
  __shared__ float sp[F_DIM];
  int fbf = flags[2];
  int g = blockIdx.x, t = threadIdx.x;
  int cn = cnt[g]; if (cn < 1) cn = 1;
  float pv = pool_sum[g * F_DIM + t] / (float)cn;
  stf(dout, fbf, PP_OFF + (long long)g * F_DIM + t, pv);
  sp[t] = pv;
  __syncthreads();
  if (t < NCLS) {
    float a = ldf(bc, fbf, t);
#pragma unroll 4
    for (int cc = 0; cc < F_DIM; ++cc) a += sp[cc] * ldf(Wc, fbf, cc * NCLS + t);
    stf(dout, fbf, LOGITS_OFF + (long long)g * NCLS + t, a);
  }
}

// ---------------------------------------------------------------------------
extern "C" void kernel_launch(void* const* d_in, const int* in_sizes, int n_in,
                              void* d_out, int out_size, void* d_ws, size_t ws_size,
                              hipStream_t stream) {
  const void* x    = d_in[0];
  const int*  ei   = (const int*)d_in[1];
  const int*  bat  = (const int*)d_in[2];
  const void* Wl   = d_in[3];
  const void* bl   = d_in[4];
  const void* Wr   = d_in[5];
  const void* br   = d_in[6];
  const void* att  = d_in[7];
  const void* bias = d_in[8];
  const void* Wc   = d_in[9];
  const void* bc   = d_in[10];

  // workspace carve — total ~8.1 MB
  char* p = (char*)d_ws;
  auto carve = [&](size_t bytes) { char* r = p; p += (bytes + 511) & ~(size_t)511; return r; };
  int*   flags    = (int*)carve(3 * 4);
  int*   zbase    = (int*)carve((size_t)ZWORDS * 4);   // deg | pool_sum | cnt
  int*   deg      = zbase;
  float* pool_sum = (float*)(zbase + N_NODES);
  int*   cnt      = zbase + N_NODES + NGRAPH * F_DIM;
  int* row_ptr  = (int*)carve((size_t)(N_NODES + 1) * 4);
  int* cursor   = (int*)carve((size_t)N_NODES * 4);
  int* csum     = (int*)carve(128 * 4);
  int* edge_src = (int*)carve((size_t)E_TOT * 4);      // 6.8 MB
  // wt aliases edge_src: wt (384 KB) is consumed by gemm_mfma, which completes
  // (stream-ordered) before fill_k writes edge_src. No overlap hazard.
  unsigned short* wt = (unsigned short*)edge_src;

  AmazonNet_36704790511894_kernel<<<1, 64, 0, stream>>>();   // template symbol no-op
  detect_k<<<1, 256, 0, stream>>>(ei, bat, (const unsigned short*)x, flags);
  zero_k<<<(ZWORDS + 255) / 256, 256, 0, stream>>>(zbase, d_out, flags);

  // linear transforms via split-bf16 MFMA: xl -> FC_OFF, xr -> PRE_OFF
  wsplit_k<<<(WT_N + 255) / 256, 256, 0, stream>>>(Wl, Wr, flags, wt);
  gemm_mfma<<<MBLK, 256, 0, stream>>>(x, wt, bl, br, d_out, flags);

  // CSR by destination
  int eblk = (E_TOT + 255) / 256;
  hist_k<<<eblk, 256, 0, stream>>>(ei, bat, flags, deg, cnt);
  int nchunk = (N_NODES + 1023) / 1024;   // 98
  scan_a<<<nchunk, 256, 0, stream>>>(deg, csum);
  scan_b<<<1, 64, 0, stream>>>(csum, row_ptr, nchunk);
  scan_c<<<nchunk, 256, 0, stream>>>(deg, csum, row_ptr, cursor);
  fill_k<<<eblk, 256, 0, stream>>>(ei, flags, cursor, edge_src);

  // attention: 300000 units, 4 per wave, 4 waves per block -> 18750 blocks
  attn1_k<<<N_UNITS_ATTN / 16, 256, 0, stream>>>(d_out, att, bias, row_ptr,
                                                 edge_src, flags);
  // finalize outputs + pooling (x4 vectorized)
  post_k<<<(int)((NODE_ELEMS / 4 + 255) / 256), 256, 0, stream>>>(d_out, bat, flags, pool_sum);
  final_k<<<NGRAPH, F_DIM, 0, stream>>>(pool_sum, cnt, Wc, bc, d_out, flags);
}

// Round 6
// 1569.003 us; speedup vs baseline: 1.3477x; 1.3477x over previous
//
#include <hip/hip_runtime.h>
#include <stdint.h>

#define N_NODES  100000
#define N_EDGES  1600000
#define E_TOT    1700000   // + self loops
#define F_DIM    192
#define IN_DIM   256
#define NGRAPH   64
#define NCLS     10
#define N_UNITS_ATTN 300000          // 100000 dst * 3 heads
#define NODE_ELEMS   19200000LL      // N_NODES * F_DIM
#define POOL_ROWS 128                // rows per pool_k block

// output element offsets (dtype-independent)
#define LOGITS_OFF 0LL
#define PRE_OFF    640LL
#define PP_OFF     19200640LL
#define FC_OFF     19212928LL

typedef __attribute__((ext_vector_type(8))) short short8v;   // 16B raw load
typedef __attribute__((ext_vector_type(8))) __bf16 bf16x8;   // MFMA A/B operand (V8y)
typedef __attribute__((ext_vector_type(4))) float f32x4;

__device__ __forceinline__ float bf2f(unsigned short u) {
  union { unsigned int i; float f; } c; c.i = ((unsigned int)u) << 16; return c.f;
}
__device__ __forceinline__ unsigned short f2bf(float f) {
  union { float f; unsigned int i; } c; c.f = f;
  unsigned int r = (c.i + 0x7FFFu + ((c.i >> 16) & 1u)) >> 16;
  return (unsigned short)r;
}
// 16B load of 8 bf16 (stored as ushort) -> properly-typed MFMA fragment
__device__ __forceinline__ bf16x8 ld_frag(const unsigned short* p) {
  return __builtin_bit_cast(bf16x8, *(const short8v*)p);
}
// dtype-aware float load/store (isbf: 1 = bf16 buffer, 0 = fp32 buffer)
__device__ __forceinline__ float ldf(const void* p, int isbf, long long i) {
  return isbf ? bf2f(((const unsigned short*)p)[i]) : ((const float*)p)[i];
}
__device__ __forceinline__ void stf(void* p, int isbf, long long i, float v) {
  if (isbf) ((unsigned short*)p)[i] = f2bf(v);
  else      ((float*)p)[i] = v;
}
// vectorized 4-channel load/store (element index i must be a multiple of 4)
__device__ __forceinline__ f32x4 ld4(const void* p, int isbf, long long i) {
  if (isbf) {
    ushort4 u = *(const ushort4*)((const unsigned short*)p + i);
    return (f32x4){bf2f(u.x), bf2f(u.y), bf2f(u.z), bf2f(u.w)};
  }
  const float4 v = *(const float4*)((const float*)p + i);
  return (f32x4){v.x, v.y, v.z, v.w};
}
__device__ __forceinline__ void st4(void* p, int isbf, long long i, f32x4 v) {
  if (isbf) {
    ushort4 u;
    u.x = f2bf(v.x); u.y = f2bf(v.y); u.z = f2bf(v.z); u.w = f2bf(v.w);
    *(ushort4*)((unsigned short*)p + i) = u;
  } else {
    float4 o; o.x = v.x; o.y = v.y; o.z = v.z; o.w = v.w;
    *(float4*)((float*)p + i) = o;
  }
}
// int32 buffer, or little-endian int64 (read low word)
__device__ __forceinline__ int ld_idx(const int* __restrict__ p, int is64, long long i) {
  return is64 ? p[i << 1] : p[(size_t)i];
}

// restore the template symbol (harness may reference it); launched as a no-op
__global__ void AmazonNet_36704790511894_kernel() {}

// ---------------------------------------------------------------------------
// dtype probe. flags[0]=ei is int64, flags[1]=batch is int64, flags[2]=floats
// are bf16.
// ---------------------------------------------------------------------------
__global__ __launch_bounds__(256) void detect_k(const int* __restrict__ ei,
                                                const int* __restrict__ bat,
                                                const unsigned short* __restrict__ x,
                                                int* __restrict__ flags) {
  __shared__ int red[3];
  int t = threadIdx.x;
  if (t < 3) red[t] = 0;
  __syncthreads();
  int o1 = 0, o2 = 0, c3 = 0;
  for (int k = t; k < N_EDGES; k += 256 * 100)   // high words if int64
    o1 |= ei[2 * k + 1];
  for (int k = t; k < 50000; k += 256)           // covers tail (batch sorted)
    o2 |= bat[2 * k + 1];
  for (int k = t; k < 4096; k += 256) {
    unsigned short u = x[2 * k];
    c3 += (((u >> 7) & 0xFF) == 0xFF);
  }
  atomicOr(&red[0], o1);
  atomicOr(&red[1], o2);
  atomicAdd(&red[2], c3);
  __syncthreads();
  if (t == 0) {
    flags[0] = (red[0] == 0);
    flags[1] = (red[1] == 0);
    flags[2] = (red[2] < 4);   // <4 NaN-pattern hits -> genuine bf16
  }
}

// ---------------------------------------------------------------------------
// zero deg|pool_sum|cnt + diagnostic sentinel in logits
// ---------------------------------------------------------------------------
#define ZWORDS (N_NODES + NGRAPH * F_DIM + NGRAPH)   // 112352
__global__ __launch_bounds__(256) void zero_k(int* __restrict__ zbase,
                                              void* __restrict__ dout,
                                              const int* __restrict__ flags) {
  int i = blockIdx.x * 256 + threadIdx.x;
  if (i < ZWORDS) zbase[i] = 0;
  if (i < NGRAPH * NCLS) stf(dout, flags[2], LOGITS_OFF + i, 0.001f);
}

// ---------------------------------------------------------------------------
// W split+transpose: W [256][192] (fp32 or bf16) -> wt[4][192][256] bf16:
//   0 = Wl_hi, 1 = Wl_lo, 2 = Wr_hi, 3 = Wr_lo   (hi = bf16 RNE, lo = bf16(v-hi))
// ---------------------------------------------------------------------------
#define WT_N 49152   // 192*256
__global__ __launch_bounds__(256) void wsplit_k(const void* __restrict__ Wl,
                                                const void* __restrict__ Wr,
                                                const int* __restrict__ flags,
                                                unsigned short* __restrict__ wt) {
  int fbf = flags[2];
  int i = blockIdx.x * 256 + threadIdx.x;   // over 49152
  if (i >= WT_N) return;
  int k = i / F_DIM, n = i - k * F_DIM;     // i = k*192 + n
  long long o = (long long)n * IN_DIM + k;  // transposed: [n][k]
  float vl = ldf(Wl, fbf, i);
  float vr = ldf(Wr, fbf, i);
  unsigned short h = f2bf(vl);
  wt[o]            = h;
  wt[WT_N + o]     = f2bf(vl - bf2f(h));
  h = f2bf(vr);
  wt[2 * WT_N + o] = h;
  wt[3 * WT_N + o] = f2bf(vr - bf2f(h));
}

// ---------------------------------------------------------------------------
// Split-bf16 MFMA GEMM: C = X@W + b for BOTH Wl and Wr in one block.
// Block = 256 thr / 4 waves, BM=64 rows; each wave owns 16 rows x full 192 cols.
// X tile staged hi/lo bf16 in LDS with XOR swizzle to break the stride-512B
// bank conflict on ds_read_b128. B-fragments read from wt (L2-resident, 384 KB).
// 3-term Markidis: acc += Ah*Bh + Al*Bh + Ah*Bl  (error ~2^-17, ok vs fp32 ref).
// xl -> FC_OFF, xr -> PRE_OFF (same placement the attention pass expects).
// ---------------------------------------------------------------------------
#define BM 64
#define MBLK ((N_NODES + BM - 1) / BM)   // 1563
__global__ __launch_bounds__(256) void gemm_mfma(const void* __restrict__ x,
                                                 const unsigned short* __restrict__ wt,
                                                 const void* __restrict__ bl,
                                                 const void* __restrict__ br,
                                                 void* __restrict__ dout,
                                                 const int* __restrict__ flags) {
  __shared__ __align__(16) unsigned short xsh[BM * IN_DIM];
  __shared__ __align__(16) unsigned short xsl[BM * IN_DIM];
  int fbf = flags[2];
  int t = threadIdx.x;
  int lane = t & 63, wv = t >> 6;
  int m0 = blockIdx.x * BM;

  // ---- stage X tile as bf16 hi/lo, swizzled ----
  // 16384 elems, each thread converts 16 chunks of 4 consecutive elements
#pragma unroll
  for (int it = 0; it < 16; ++it) {
    int idx = (it * 256 + t) * 4;        // tile element index = row*256 + k
    int row = idx >> 8;
    int grow = m0 + row;
    ushort4 h4, l4;
    float v0 = 0.f, v1 = 0.f, v2 = 0.f, v3 = 0.f;
    if (grow < N_NODES) {
      long long g = (long long)grow * IN_DIM + (idx & 255);
      v0 = ldf(x, fbf, g);
      v1 = ldf(x, fbf, g + 1);
      v2 = ldf(x, fbf, g + 2);
      v3 = ldf(x, fbf, g + 3);
    }
    h4.x = f2bf(v0); l4.x = f2bf(v0 - bf2f(h4.x));
    h4.y = f2bf(v1); l4.y = f2bf(v1 - bf2f(h4.y));
    h4.z = f2bf(v2); l4.z = f2bf(v2 - bf2f(h4.z));
    h4.w = f2bf(v3); l4.w = f2bf(v3 - bf2f(h4.w));
    int sidx = idx ^ ((row & 7) << 3);   // element-index swizzle (multiple of 8)
    *(ushort4*)&xsh[sidx] = h4;
    *(ushort4*)&xsl[sidx] = l4;
  }
  __syncthreads();

  // ---- MFMA main loop ----
  f32x4 accL[12], accR[12];
#pragma unroll
  for (int n = 0; n < 12; ++n) {
    accL[n] = (f32x4){0.f, 0.f, 0.f, 0.f};
    accR[n] = (f32x4){0.f, 0.f, 0.f, 0.f};
  }
  int r = lane & 15, kq = lane >> 4;
  int arow = wv * 16 + r;
  const unsigned short* wlh = wt;
  const unsigned short* wll = wt + WT_N;
  const unsigned short* wrh = wt + 2 * WT_N;
  const unsigned short* wrl = wt + 3 * WT_N;

  for (int ks = 0; ks < 8; ++ks) {
    int k0 = ks * 32 + kq * 8;
    int sidx = (arow * IN_DIM + k0) ^ ((arow & 7) << 3);
    bf16x8 ah = ld_frag(&xsh[sidx]);
    bf16x8 al = ld_frag(&xsl[sidx]);
#pragma unroll
    for (int n = 0; n < 12; ++n) {
      long long wo = (long long)(n * 16 + r) * IN_DIM + k0;
      bf16x8 blh = ld_frag(&wlh[wo]);
      bf16x8 bll = ld_frag(&wll[wo]);
      bf16x8 brh = ld_frag(&wrh[wo]);
      bf16x8 brl = ld_frag(&wrl[wo]);
      accL[n] = __builtin_amdgcn_mfma_f32_16x16x32_bf16(ah, blh, accL[n], 0, 0, 0);
      accL[n] = __builtin_amdgcn_mfma_f32_16x16x32_bf16(al, blh, accL[n], 0, 0, 0);
      accL[n] = __builtin_amdgcn_mfma_f32_16x16x32_bf16(ah, bll, accL[n], 0, 0, 0);
      accR[n] = __builtin_amdgcn_mfma_f32_16x16x32_bf16(ah, brh, accR[n], 0, 0, 0);
      accR[n] = __builtin_amdgcn_mfma_f32_16x16x32_bf16(al, brh, accR[n], 0, 0, 0);
      accR[n] = __builtin_amdgcn_mfma_f32_16x16x32_bf16(ah, brl, accR[n], 0, 0, 0);
    }
  }

  // ---- epilogue: C/D layout col=lane&15, row=(lane>>4)*4+reg (m89-verified) ----
  int orow0 = m0 + wv * 16 + (lane >> 4) * 4;
  int colr = lane & 15;
#pragma unroll
  for (int n = 0; n < 12; ++n) {
    int c = n * 16 + colr;
    float bLv = ldf(bl, fbf, c);
    float bRv = ldf(br, fbf, c);
#pragma unroll
    for (int rr = 0; rr < 4; ++rr) {
      int grow = orow0 + rr;
      if (grow < N_NODES) {
        stf(dout, fbf, FC_OFF  + (long long)grow * F_DIM + c, accL[n][rr] + bLv);
        stf(dout, fbf, PRE_OFF + (long long)grow * F_DIM + c, accR[n][rr] + bRv);
      }
    }
  }
}

// ---------------------------------------------------------------------------
// CSR build by destination
// ---------------------------------------------------------------------------
__global__ __launch_bounds__(256) void hist_k(const int* __restrict__ ei,
                                              const int* __restrict__ batch,
                                              const int* __restrict__ flags,
                                              int* __restrict__ deg,
                                              int* __restrict__ cnt) {
  int is64e = flags[0], is64b = flags[1];
  int e = blockIdx.x * 256 + threadIdx.x;
  if (e < E_TOT) {
    int s, d;
    if (e < N_EDGES) {
      s = ld_idx(ei, is64e, e);
      d = ld_idx(ei, is64e, (long long)N_EDGES + e);
    } else s = d = e - N_EDGES;
    if ((unsigned)d < (unsigned)N_NODES && (unsigned)s < (unsigned)N_NODES)
      atomicAdd(&deg[d], 1);
  }
  if (e < N_NODES) {
    int g = ld_idx(batch, is64b, e);
    if ((unsigned)g < (unsigned)NGRAPH) atomicAdd(&cnt[g], 1);
  }
}

__global__ __launch_bounds__(256) void scan_a(const int* __restrict__ deg, int* __restrict__ csum) {
  __shared__ int red[256];
  int b = blockIdx.x, t = threadIdx.x;
  int base = b * 1024 + t * 4;
  int s = 0;
#pragma unroll
  for (int k = 0; k < 4; ++k) { int idx = base + k; if (idx < N_NODES) s += deg[idx]; }
  red[t] = s;
  __syncthreads();
  for (int off = 128; off; off >>= 1) {
    if (t < off) red[t] += red[t + off];
    __syncthreads();
  }
  if (t == 0) csum[b] = red[0];
}

__global__ void scan_b(int* csum, int* row_ptr, int nblk) {
  if (threadIdx.x == 0 && blockIdx.x == 0) {
    int run = 0;
    for (int b = 0; b < nblk; ++b) { int s = csum[b]; csum[b] = run; run += s; }
    row_ptr[N_NODES] = run;
  }
}

__global__ __launch_bounds__(256) void scan_c(const int* __restrict__ deg,
                                              const int* __restrict__ csum,
                                              int* __restrict__ row_ptr,
                                              int* __restrict__ cursor) {
  __shared__ int tsum[256];
  int b = blockIdx.x, t = threadIdx.x;
  int base = b * 1024 + t * 4;
  int v[4];
  int s = 0;
#pragma unroll
  for (int k = 0; k < 4; ++k) {
    int idx = base + k;
    v[k] = (idx < N_NODES) ? deg[idx] : 0;
    s += v[k];
  }
  tsum[t] = s;
  __syncthreads();
  for (int off = 1; off < 256; off <<= 1) {
    int x = (t >= off) ? tsum[t - off] : 0;
    __syncthreads();
    tsum[t] += x;
    __syncthreads();
  }
  int run = csum[b] + tsum[t] - s;
#pragma unroll
  for (int k = 0; k < 4; ++k) {
    int idx = base + k;
    if (idx < N_NODES) { row_ptr[idx] = run; cursor[idx] = run; }
    run += v[k];
  }
}

__global__ __launch_bounds__(256) void fill_k(const int* __restrict__ ei,
                                              const int* __restrict__ flags,
                                              int* __restrict__ cursor,
                                              int* __restrict__ edge_src) {
  int is64e = flags[0];
  int e = blockIdx.x * 256 + threadIdx.x;
  if (e >= E_TOT) return;
  int s, d;
  if (e < N_EDGES) {
    s = ld_idx(ei, is64e, e);
    d = ld_idx(ei, is64e, (long long)N_EDGES + e);
  } else s = d = e - N_EDGES;
  if ((unsigned)d < (unsigned)N_NODES && (unsigned)s < (unsigned)N_NODES) {
    int pos = atomicAdd(&cursor[d], 1);
    edge_src[pos] = s;
  }
}

// ---------------------------------------------------------------------------
// Pass 1: one 16-lane unit per (dst, head); 4 units per wave.
// Each lane owns 4 channels (float4). Units 0-2 of a wave are the 3 heads of
// the same dst -> shared edge list, gathers coalesce to one contiguous row.
// 4 independent dep-chains per wave hide gather latency; reduce is 4 shfl.
// xl at FC_OFF (read-only), xr at PRE_OFF; result overwrites PRE_OFF slot.
// ---------------------------------------------------------------------------
__global__ __launch_bounds__(256) void attn1_k(void* __restrict__ dout,
                                               const void* __restrict__ att,
                                               const void* __restrict__ bias,
                                               const int* __restrict__ row_ptr,
                                               const int* __restrict__ edge_src,
                                               const int* __restrict__ flags) {
  int fbf = flags[2];
  int lane = threadIdx.x & 63;
  int wid = (blockIdx.x * 256 + threadIdx.x) >> 6;   // global wave id
  int gu = wid * 4 + (lane >> 4);                    // unit id = dst*3 + head
  if (gu >= N_UNITS_ATTN) return;                    // grid exact: never taken
  int i = gu / 3;
  int h = gu - i * 3;
  int sl = lane & 15;
  int c0 = h * 64 + sl * 4;                          // 4 channels per lane

  f32x4 xr4 = ld4(dout, fbf, PRE_OFF + (long long)i * F_DIM + c0);
  f32x4 at4 = ld4(att, fbf, c0);
  int start = row_ptr[i];
  int deg   = row_ptr[i + 1] - start;

  // wave-wide max degree (deg uniform within each 16-lane unit)
  int dm = deg;
  dm = max(dm, __shfl_xor(dm, 16));
  dm = max(dm, __shfl_xor(dm, 32));

  float m = -1e30f, s = 0.f;
  f32x4 o = (f32x4){0.f, 0.f, 0.f, 0.f};
  f32x4 xlc = (f32x4){0.f, 0.f, 0.f, 0.f};
  if (deg > 0)
    xlc = ld4(dout, fbf, FC_OFF + (long long)edge_src[start] * F_DIM + c0);

  for (int e = 0; e < dm; ++e) {
    f32x4 xln = (f32x4){0.f, 0.f, 0.f, 0.f};
    if (e + 1 < deg)
      xln = ld4(dout, fbf, FC_OFF + (long long)edge_src[start + e + 1] * F_DIM + c0);
    if (e < deg) {
      f32x4 tt = xlc + xr4;
      tt.x = tt.x > 0.f ? tt.x : 0.2f * tt.x;        // GATv2 leaky_relu, slope 0.2
      tt.y = tt.y > 0.f ? tt.y : 0.2f * tt.y;
      tt.z = tt.z > 0.f ? tt.z : 0.2f * tt.z;
      tt.w = tt.w > 0.f ? tt.w : 0.2f * tt.w;
      float pp = tt.x * at4.x + tt.y * at4.y + tt.z * at4.z + tt.w * at4.w;
#pragma unroll
      for (int d = 1; d < 16; d <<= 1) pp += __shfl_xor(pp, d);  // unit-level sum
      float mn = fmaxf(m, pp);
      float cf = __expf(m - mn);
      float w  = __expf(pp - mn);
      s = s * cf + w;
      o.x = o.x * cf + w * xlc.x;
      o.y = o.y * cf + w * xlc.y;
      o.z = o.z * cf + w * xlc.z;
      o.w = o.w * cf + w * xlc.w;
      m = mn;
    }
    xlc = xln;
  }
  float inv = (s > 0.f) ? 1.f / s : 0.f;
  f32x4 b4 = ld4(bias, fbf, c0);
  f32x4 val;
  val.x = o.x * inv + b4.x;
  val.y = o.y * inv + b4.y;
  val.z = o.z * inv + b4.z;
  val.w = o.w * inv + b4.w;
  st4(dout, fbf, PRE_OFF + (long long)i * F_DIM + c0, val);
}

// ---------------------------------------------------------------------------
// Pass 2 (pure streaming, x4): fc (at PRE_OFF) -> out_fc; leaky_relu -> out_pre.
// NO atomics — pooling moved to pool_k (the 19.2M same-address atomics were
// the 685 us / 450 MB-write bottleneck in R5's profile).
// ---------------------------------------------------------------------------
__global__ __launch_bounds__(256) void post_k(void* __restrict__ dout,
                                              const int* __restrict__ flags) {
  int fbf = flags[2];
  long long idx = ((long long)blockIdx.x * 256 + threadIdx.x) * 4;
  if (idx >= NODE_ELEMS) return;
  f32x4 fc = ld4(dout, fbf, PRE_OFF + idx);
  st4(dout, fbf, FC_OFF + idx, fc);
  f32x4 pre;
  pre.x = fc.x > 0.f ? fc.x : 0.01f * fc.x;        // F.leaky_relu default slope
  pre.y = fc.y > 0.f ? fc.y : 0.01f * fc.y;
  pre.z = fc.z > 0.f ? fc.z : 0.01f * fc.z;
  pre.w = fc.w > 0.f ? fc.w : 0.01f * fc.w;
  st4(dout, fbf, PRE_OFF + idx, pre);
}

// ---------------------------------------------------------------------------
// Pooling: batch is SORTED, so per-graph node ranges are contiguous. One
// 192-thread block per POOL_ROWS-row chunk; thread t owns channel t and
// accumulates in a register, flushing to pool_sum only on graph change
// (~1.2 atomics/thread total vs 1 atomic/element before).
// ---------------------------------------------------------------------------
__global__ __launch_bounds__(192) void pool_k(const void* __restrict__ dout,
                                              const int* __restrict__ batch,
                                              const int* __restrict__ flags,
                                              float* __restrict__ pool_sum) {
  int fbf = flags[2], is64b = flags[1];
  int t = threadIdx.x;                       // channel
  int r0 = blockIdx.x * POOL_ROWS;
  int rend = r0 + POOL_ROWS;
  if (rend > N_NODES) rend = N_NODES;
  if (r0 >= N_NODES) return;
  float acc = 0.f;
  int gcur = ld_idx(batch, is64b, r0);
  for (int r = r0; r < rend; ++r) {
    int g = ld_idx(batch, is64b, r);
    if (g != gcur) {
      if ((unsigned)gcur < (unsigned)NGRAPH)
        atomicAdd(&pool_sum[gcur * F_DIM + t], acc);
      acc = 0.f;
      gcur = g;
    }
    acc += ldf(dout, fbf, PRE_OFF + (long long)r * F_DIM + t);
  }
  if ((unsigned)gcur < (unsigned)NGRAPH)
    atomicAdd(&pool_sum[gcur * F_DIM + t], acc);
}

// ---------------------------------------------------------------------------
__global__ __launch_bounds__(192) void final_k(const float* __restrict__ pool_sum,
                                               const int* __restrict__ cnt,
                                               const void* __restrict__ Wc,
                                               const void* __restrict__ bc,
                                               void* __restrict__ dout,
                                               const int* __restrict__ flags) {
  __shared__ float sp[F_DIM];
  int fbf = flags[2];
  int g = blockIdx.x, t = threadIdx.x;
  int cn = cnt[g]; if (cn < 1) cn = 1;
  float pv = pool_sum[g * F_DIM + t] / (float)cn;
  stf(dout, fbf, PP_OFF + (long long)g * F_DIM + t, pv);
  sp[t] = pv;
  __syncthreads();
  if (t < NCLS) {
    float a = ldf(bc, fbf, t);
#pragma unroll 4
    for (int cc = 0; cc < F_DIM; ++cc) a += sp[cc] * ldf(Wc, fbf, cc * NCLS + t);
    stf(dout, fbf, LOGITS_OFF + (long long)g * NCLS + t, a);
  }
}

// ---------------------------------------------------------------------------
extern "C" void kernel_launch(void* const* d_in, const int* in_sizes, int n_in,
                              void* d_out, int out_size, void* d_ws, size_t ws_size,
                              hipStream_t stream) {
  const void* x    = d_in[0];
  const int*  ei   = (const int*)d_in[1];
  const int*  bat  = (const int*)d_in[2];
  const void* Wl   = d_in[3];
  const void* bl   = d_in[4];
  const void* Wr   = d_in[5];
  const void* br   = d_in[6];
  const void* att  = d_in[7];
  const void* bias = d_in[8];
  const void* Wc   = d_in[9];
  const void* bc   = d_in[10];

  // workspace carve — total ~8.1 MB
  char* p = (char*)d_ws;
  auto carve = [&](size_t bytes) { char* r = p; p += (bytes + 511) & ~(size_t)511; return r; };
  int*   flags    = (int*)carve(3 * 4);
  int*   zbase    = (int*)carve((size_t)ZWORDS * 4);   // deg | pool_sum | cnt
  int*   deg      = zbase;
  float* pool_sum = (float*)(zbase + N_NODES);
  int*   cnt      = zbase + N_NODES + NGRAPH * F_DIM;
  int* row_ptr  = (int*)carve((size_t)(N_NODES + 1) * 4);
  int* cursor   = (int*)carve((size_t)N_NODES * 4);
  int* csum     = (int*)carve(128 * 4);
  int* edge_src = (int*)carve((size_t)E_TOT * 4);      // 6.8 MB
  // wt aliases edge_src: wt (384 KB) is consumed by gemm_mfma, which completes
  // (stream-ordered) before fill_k writes edge_src. No overlap hazard.
  unsigned short* wt = (unsigned short*)edge_src;

  AmazonNet_36704790511894_kernel<<<1, 64, 0, stream>>>();   // template symbol no-op
  detect_k<<<1, 256, 0, stream>>>(ei, bat, (const unsigned short*)x, flags);
  zero_k<<<(ZWORDS + 255) / 256, 256, 0, stream>>>(zbase, d_out, flags);

  // linear transforms via split-bf16 MFMA: xl -> FC_OFF, xr -> PRE_OFF
  wsplit_k<<<(WT_N + 255) / 256, 256, 0, stream>>>(Wl, Wr, flags, wt);
  gemm_mfma<<<MBLK, 256, 0, stream>>>(x, wt, bl, br, d_out, flags);

  // CSR by destination
  int eblk = (E_TOT + 255) / 256;
  hist_k<<<eblk, 256, 0, stream>>>(ei, bat, flags, deg, cnt);
  int nchunk = (N_NODES + 1023) / 1024;   // 98
  scan_a<<<nchunk, 256, 0, stream>>>(deg, csum);
  scan_b<<<1, 64, 0, stream>>>(csum, row_ptr, nchunk);
  scan_c<<<nchunk, 256, 0, stream>>>(deg, csum, row_ptr, cursor);
  fill_k<<<eblk, 256, 0, stream>>>(ei, flags, cursor, edge_src);

  // attention: 300000 units, 4 per wave, 4 waves per block -> 18750 blocks
  attn1_k<<<N_UNITS_ATTN / 16, 256, 0, stream>>>(d_out, att, bias, row_ptr,
                                                 edge_src, flags);
  // finalize outputs (pure streaming), then register-accumulated pooling
  post_k<<<(int)((NODE_ELEMS / 4 + 255) / 256), 256, 0, stream>>>(d_out, flags);
  pool_k<<<(N_NODES + POOL_ROWS - 1) / POOL_ROWS, 192, 0, stream>>>(d_out, bat, flags, pool_sum);
  final_k<<<NGRAPH, F_DIM, 0, stream>>>(pool_sum, cnt, Wc, bc, d_out, flags);
}

// Round 7
// 1178.499 us; speedup vs baseline: 1.7942x; 1.3314x over previous
//
#include <hip/hip_runtime.h>
#include <stdint.h>

#define N_NODES  100000
#define N_EDGES  1600000
#define E_TOT    1700000   // + self loops
#define F_DIM    192
#define IN_DIM   256
#define NGRAPH   64
#define NCLS     10
#define N_UNITS_ATTN 300000          // 100000 dst * 3 heads
#define NODE_ELEMS   19200000LL      // N_NODES * F_DIM
#define POOL_ROWS 128                // rows per pool_k block

// output element offsets (dtype-independent)
#define LOGITS_OFF 0LL
#define PRE_OFF    640LL
#define PP_OFF     19200640LL
#define FC_OFF     19212928LL

typedef __attribute__((ext_vector_type(8))) short short8v;   // 16B raw load
typedef __attribute__((ext_vector_type(8))) __bf16 bf16x8;   // MFMA A/B operand (V8y)
typedef __attribute__((ext_vector_type(4))) float f32x4;

__device__ __forceinline__ float bf2f(unsigned short u) {
  union { unsigned int i; float f; } c; c.i = ((unsigned int)u) << 16; return c.f;
}
__device__ __forceinline__ unsigned short f2bf(float f) {
  union { float f; unsigned int i; } c; c.f = f;
  unsigned int r = (c.i + 0x7FFFu + ((c.i >> 16) & 1u)) >> 16;
  return (unsigned short)r;
}
// 16B load of 8 bf16 (stored as ushort) -> properly-typed MFMA fragment
__device__ __forceinline__ bf16x8 ld_frag(const unsigned short* p) {
  return __builtin_bit_cast(bf16x8, *(const short8v*)p);
}
// dtype-aware float load/store (isbf: 1 = bf16 buffer, 0 = fp32 buffer)
__device__ __forceinline__ float ldf(const void* p, int isbf, long long i) {
  return isbf ? bf2f(((const unsigned short*)p)[i]) : ((const float*)p)[i];
}
__device__ __forceinline__ void stf(void* p, int isbf, long long i, float v) {
  if (isbf) ((unsigned short*)p)[i] = f2bf(v);
  else      ((float*)p)[i] = v;
}
// vectorized 4-channel load/store (element index i must be a multiple of 4)
__device__ __forceinline__ f32x4 ld4(const void* p, int isbf, long long i) {
  if (isbf) {
    ushort4 u = *(const ushort4*)((const unsigned short*)p + i);
    return (f32x4){bf2f(u.x), bf2f(u.y), bf2f(u.z), bf2f(u.w)};
  }
  const float4 v = *(const float4*)((const float*)p + i);
  return (f32x4){v.x, v.y, v.z, v.w};
}
__device__ __forceinline__ void st4(void* p, int isbf, long long i, f32x4 v) {
  if (isbf) {
    ushort4 u;
    u.x = f2bf(v.x); u.y = f2bf(v.y); u.z = f2bf(v.z); u.w = f2bf(v.w);
    *(ushort4*)((unsigned short*)p + i) = u;
  } else {
    float4 o; o.x = v.x; o.y = v.y; o.z = v.z; o.w = v.w;
    *(float4*)((float*)p + i) = o;
  }
}
// int32 buffer, or little-endian int64 (read low word)
__device__ __forceinline__ int ld_idx(const int* __restrict__ p, int is64, long long i) {
  return is64 ? p[i << 1] : p[(size_t)i];
}

// restore the template symbol (harness may reference it); launched as a no-op
__global__ void AmazonNet_36704790511894_kernel() {}

// ---------------------------------------------------------------------------
// dtype probe. flags[0]=ei is int64, flags[1]=batch is int64, flags[2]=floats
// are bf16.
// ---------------------------------------------------------------------------
__global__ __launch_bounds__(256) void detect_k(const int* __restrict__ ei,
                                                const int* __restrict__ bat,
                                                const unsigned short* __restrict__ x,
                                                int* __restrict__ flags) {
  __shared__ int red[3];
  int t = threadIdx.x;
  if (t < 3) red[t] = 0;
  __syncthreads();
  int o1 = 0, o2 = 0, c3 = 0;
  for (int k = t; k < N_EDGES; k += 256 * 100)   // high words if int64
    o1 |= ei[2 * k + 1];
  for (int k = t; k < 50000; k += 256)           // covers tail (batch sorted)
    o2 |= bat[2 * k + 1];
  for (int k = t; k < 4096; k += 256) {
    unsigned short u = x[2 * k];
    c3 += (((u >> 7) & 0xFF) == 0xFF);
  }
  atomicOr(&red[0], o1);
  atomicOr(&red[1], o2);
  atomicAdd(&red[2], c3);
  __syncthreads();
  if (t == 0) {
    flags[0] = (red[0] == 0);
    flags[1] = (red[1] == 0);
    flags[2] = (red[2] < 4);   // <4 NaN-pattern hits -> genuine bf16
  }
}

// ---------------------------------------------------------------------------
// init deg=1 (self-loop pre-counted) | pool_sum=0 + sentinel in logits
// ---------------------------------------------------------------------------
#define ZWORDS (N_NODES + NGRAPH * F_DIM)   // 112288
__global__ __launch_bounds__(256) void zero_k(int* __restrict__ zbase,
                                              void* __restrict__ dout,
                                              const int* __restrict__ flags) {
  int i = blockIdx.x * 256 + threadIdx.x;
  if (i < N_NODES) zbase[i] = 1;             // deg starts at 1 (self-loop)
  else if (i < ZWORDS) zbase[i] = 0;         // pool_sum
  if (i < NGRAPH * NCLS) stf(dout, flags[2], LOGITS_OFF + i, 0.001f);
}

// ---------------------------------------------------------------------------
// W split+transpose: W [256][192] (fp32 or bf16) -> wt[4][192][256] bf16:
//   0 = Wl_hi, 1 = Wl_lo, 2 = Wr_hi, 3 = Wr_lo   (hi = bf16 RNE, lo = bf16(v-hi))
// ---------------------------------------------------------------------------
#define WT_N 49152   // 192*256
__global__ __launch_bounds__(256) void wsplit_k(const void* __restrict__ Wl,
                                                const void* __restrict__ Wr,
                                                const int* __restrict__ flags,
                                                unsigned short* __restrict__ wt) {
  int fbf = flags[2];
  int i = blockIdx.x * 256 + threadIdx.x;   // over 49152
  if (i >= WT_N) return;
  int k = i / F_DIM, n = i - k * F_DIM;     // i = k*192 + n
  long long o = (long long)n * IN_DIM + k;  // transposed: [n][k]
  float vl = ldf(Wl, fbf, i);
  float vr = ldf(Wr, fbf, i);
  unsigned short h = f2bf(vl);
  wt[o]            = h;
  wt[WT_N + o]     = f2bf(vl - bf2f(h));
  h = f2bf(vr);
  wt[2 * WT_N + o] = h;
  wt[3 * WT_N + o] = f2bf(vr - bf2f(h));
}

// ---------------------------------------------------------------------------
// Split-bf16 MFMA GEMM: C = X@W + b for BOTH Wl and Wr in one block.
// ---------------------------------------------------------------------------
#define BM 64
#define MBLK ((N_NODES + BM - 1) / BM)   // 1563
__global__ __launch_bounds__(256) void gemm_mfma(const void* __restrict__ x,
                                                 const unsigned short* __restrict__ wt,
                                                 const void* __restrict__ bl,
                                                 const void* __restrict__ br,
                                                 void* __restrict__ dout,
                                                 const int* __restrict__ flags) {
  __shared__ __align__(16) unsigned short xsh[BM * IN_DIM];
  __shared__ __align__(16) unsigned short xsl[BM * IN_DIM];
  int fbf = flags[2];
  int t = threadIdx.x;
  int lane = t & 63, wv = t >> 6;
  int m0 = blockIdx.x * BM;

  // ---- stage X tile as bf16 hi/lo, swizzled ----
#pragma unroll
  for (int it = 0; it < 16; ++it) {
    int idx = (it * 256 + t) * 4;        // tile element index = row*256 + k
    int row = idx >> 8;
    int grow = m0 + row;
    ushort4 h4, l4;
    float v0 = 0.f, v1 = 0.f, v2 = 0.f, v3 = 0.f;
    if (grow < N_NODES) {
      long long g = (long long)grow * IN_DIM + (idx & 255);
      v0 = ldf(x, fbf, g);
      v1 = ldf(x, fbf, g + 1);
      v2 = ldf(x, fbf, g + 2);
      v3 = ldf(x, fbf, g + 3);
    }
    h4.x = f2bf(v0); l4.x = f2bf(v0 - bf2f(h4.x));
    h4.y = f2bf(v1); l4.y = f2bf(v1 - bf2f(h4.y));
    h4.z = f2bf(v2); l4.z = f2bf(v2 - bf2f(h4.z));
    h4.w = f2bf(v3); l4.w = f2bf(v3 - bf2f(h4.w));
    int sidx = idx ^ ((row & 7) << 3);   // element-index swizzle (multiple of 8)
    *(ushort4*)&xsh[sidx] = h4;
    *(ushort4*)&xsl[sidx] = l4;
  }
  __syncthreads();

  // ---- MFMA main loop ----
  f32x4 accL[12], accR[12];
#pragma unroll
  for (int n = 0; n < 12; ++n) {
    accL[n] = (f32x4){0.f, 0.f, 0.f, 0.f};
    accR[n] = (f32x4){0.f, 0.f, 0.f, 0.f};
  }
  int r = lane & 15, kq = lane >> 4;
  int arow = wv * 16 + r;
  const unsigned short* wlh = wt;
  const unsigned short* wll = wt + WT_N;
  const unsigned short* wrh = wt + 2 * WT_N;
  const unsigned short* wrl = wt + 3 * WT_N;

  for (int ks = 0; ks < 8; ++ks) {
    int k0 = ks * 32 + kq * 8;
    int sidx = (arow * IN_DIM + k0) ^ ((arow & 7) << 3);
    bf16x8 ah = ld_frag(&xsh[sidx]);
    bf16x8 al = ld_frag(&xsl[sidx]);
#pragma unroll
    for (int n = 0; n < 12; ++n) {
      long long wo = (long long)(n * 16 + r) * IN_DIM + k0;
      bf16x8 blh = ld_frag(&wlh[wo]);
      bf16x8 bll = ld_frag(&wll[wo]);
      bf16x8 brh = ld_frag(&wrh[wo]);
      bf16x8 brl = ld_frag(&wrl[wo]);
      accL[n] = __builtin_amdgcn_mfma_f32_16x16x32_bf16(ah, blh, accL[n], 0, 0, 0);
      accL[n] = __builtin_amdgcn_mfma_f32_16x16x32_bf16(al, blh, accL[n], 0, 0, 0);
      accL[n] = __builtin_amdgcn_mfma_f32_16x16x32_bf16(ah, bll, accL[n], 0, 0, 0);
      accR[n] = __builtin_amdgcn_mfma_f32_16x16x32_bf16(ah, brh, accR[n], 0, 0, 0);
      accR[n] = __builtin_amdgcn_mfma_f32_16x16x32_bf16(al, brh, accR[n], 0, 0, 0);
      accR[n] = __builtin_amdgcn_mfma_f32_16x16x32_bf16(ah, brl, accR[n], 0, 0, 0);
    }
  }

  // ---- epilogue: C/D layout col=lane&15, row=(lane>>4)*4+reg (m89-verified) ----
  int orow0 = m0 + wv * 16 + (lane >> 4) * 4;
  int colr = lane & 15;
#pragma unroll
  for (int n = 0; n < 12; ++n) {
    int c = n * 16 + colr;
    float bLv = ldf(bl, fbf, c);
    float bRv = ldf(br, fbf, c);
#pragma unroll
    for (int rr = 0; rr < 4; ++rr) {
      int grow = orow0 + rr;
      if (grow < N_NODES) {
        stf(dout, fbf, FC_OFF  + (long long)grow * F_DIM + c, accL[n][rr] + bLv);
        stf(dout, fbf, PRE_OFF + (long long)grow * F_DIM + c, accR[n][rr] + bRv);
      }
    }
  }
}

// ---------------------------------------------------------------------------
// CSR build by destination. hist_k: deg atomics (random addr, real edges only)
// + graph boundaries via sorted-batch neighbor compare (plain stores, NO
// same-address atomics — those were R6's 433us serialization).
// ---------------------------------------------------------------------------
__global__ __launch_bounds__(256) void hist_k(const int* __restrict__ ei,
                                              const int* __restrict__ batch,
                                              const int* __restrict__ flags,
                                              int* __restrict__ deg,
                                              int* __restrict__ gbound) {
  int is64e = flags[0], is64b = flags[1];
  int e = blockIdx.x * 256 + threadIdx.x;
  if (e < N_EDGES) {
    int s = ld_idx(ei, is64e, e);
    int d = ld_idx(ei, is64e, (long long)N_EDGES + e);
    if ((unsigned)d < (unsigned)N_NODES && (unsigned)s < (unsigned)N_NODES)
      atomicAdd(&deg[d], 1);
  }
  if (e < N_NODES) {
    int bi = ld_idx(batch, is64b, e);
    if (bi < 0) bi = 0;
    if (bi >= NGRAPH) bi = NGRAPH - 1;
    int bp = -1;
    if (e > 0) {
      bp = ld_idx(batch, is64b, e - 1);
      if (bp < 0) bp = 0;
      if (bp >= NGRAPH) bp = NGRAPH - 1;
    }
    for (int g = bp + 1; g <= bi; ++g) gbound[g] = e;       // boundary stores
    if (e == N_NODES - 1)
      for (int g = bi + 1; g <= NGRAPH; ++g) gbound[g] = N_NODES;
  }
}

__global__ __launch_bounds__(256) void scan_a(const int* __restrict__ deg, int* __restrict__ csum) {
  __shared__ int red[256];
  int b = blockIdx.x, t = threadIdx.x;
  int base = b * 1024 + t * 4;
  int s = 0;
#pragma unroll
  for (int k = 0; k < 4; ++k) { int idx = base + k; if (idx < N_NODES) s += deg[idx]; }
  red[t] = s;
  __syncthreads();
  for (int off = 128; off; off >>= 1) {
    if (t < off) red[t] += red[t + off];
    __syncthreads();
  }
  if (t == 0) csum[b] = red[0];
}

__global__ void scan_b(int* csum, int* row_ptr, int nblk) {
  if (threadIdx.x == 0 && blockIdx.x == 0) {
    int run = 0;
    for (int b = 0; b < nblk; ++b) { int s = csum[b]; csum[b] = run; run += s; }
    row_ptr[N_NODES] = run;
  }
}

// scan_c also places each node's self-loop at CSR slot 0 (non-atomic) and
// starts the fill cursor at slot 1.
__global__ __launch_bounds__(256) void scan_c(const int* __restrict__ deg,
                                              const int* __restrict__ csum,
                                              int* __restrict__ row_ptr,
                                              int* __restrict__ cursor,
                                              int* __restrict__ edge_src) {
  __shared__ int tsum[256];
  int b = blockIdx.x, t = threadIdx.x;
  int base = b * 1024 + t * 4;
  int v[4];
  int s = 0;
#pragma unroll
  for (int k = 0; k < 4; ++k) {
    int idx = base + k;
    v[k] = (idx < N_NODES) ? deg[idx] : 0;
    s += v[k];
  }
  tsum[t] = s;
  __syncthreads();
  for (int off = 1; off < 256; off <<= 1) {
    int x = (t >= off) ? tsum[t - off] : 0;
    __syncthreads();
    tsum[t] += x;
    __syncthreads();
  }
  int run = csum[b] + tsum[t] - s;
#pragma unroll
  for (int k = 0; k < 4; ++k) {
    int idx = base + k;
    if (idx < N_NODES) {
      row_ptr[idx] = run;
      cursor[idx] = run + 1;     // slot 0 reserved for self-loop
      edge_src[run] = idx;       // self-loop placed deterministically
    }
    run += v[k];
  }
}

__global__ __launch_bounds__(256) void fill_k(const int* __restrict__ ei,
                                              const int* __restrict__ flags,
                                              int* __restrict__ cursor,
                                              int* __restrict__ edge_src) {
  int is64e = flags[0];
  int e = blockIdx.x * 256 + threadIdx.x;
  if (e >= N_EDGES) return;
  int s = ld_idx(ei, is64e, e);
  int d = ld_idx(ei, is64e, (long long)N_EDGES + e);
  if ((unsigned)d < (unsigned)N_NODES && (unsigned)s < (unsigned)N_NODES) {
    int pos = atomicAdd(&cursor[d], 1);
    edge_src[pos] = s;
  }
}

// ---------------------------------------------------------------------------
// Pass 1: one 16-lane unit per (dst, head); 4 units per wave.
// ---------------------------------------------------------------------------
__global__ __launch_bounds__(256) void attn1_k(void* __restrict__ dout,
                                               const void* __restrict__ att,
                                               const void* __restrict__ bias,
                                               const int* __restrict__ row_ptr,
                                               const int* __restrict__ edge_src,
                                               const int* __restrict__ flags) {
  int fbf = flags[2];
  int lane = threadIdx.x & 63;
  int wid = (blockIdx.x * 256 + threadIdx.x) >> 6;   // global wave id
  int gu = wid * 4 + (lane >> 4);                    // unit id = dst*3 + head
  if (gu >= N_UNITS_ATTN) return;                    // grid exact: never taken
  int i = gu / 3;
  int h = gu - i * 3;
  int sl = lane & 15;
  int c0 = h * 64 + sl * 4;                          // 4 channels per lane

  f32x4 xr4 = ld4(dout, fbf, PRE_OFF + (long long)i * F_DIM + c0);
  f32x4 at4 = ld4(att, fbf, c0);
  int start = row_ptr[i];
  int deg   = row_ptr[i + 1] - start;

  // wave-wide max degree (deg uniform within each 16-lane unit)
  int dm = deg;
  dm = max(dm, __shfl_xor(dm, 16));
  dm = max(dm, __shfl_xor(dm, 32));

  float m = -1e30f, s = 0.f;
  f32x4 o = (f32x4){0.f, 0.f, 0.f, 0.f};
  f32x4 xlc = (f32x4){0.f, 0.f, 0.f, 0.f};
  if (deg > 0)
    xlc = ld4(dout, fbf, FC_OFF + (long long)edge_src[start] * F_DIM + c0);

  for (int e = 0; e < dm; ++e) {
    f32x4 xln = (f32x4){0.f, 0.f, 0.f, 0.f};
    if (e + 1 < deg)
      xln = ld4(dout, fbf, FC_OFF + (long long)edge_src[start + e + 1] * F_DIM + c0);
    if (e < deg) {
      f32x4 tt = xlc + xr4;
      tt.x = tt.x > 0.f ? tt.x : 0.2f * tt.x;        // GATv2 leaky_relu, slope 0.2
      tt.y = tt.y > 0.f ? tt.y : 0.2f * tt.y;
      tt.z = tt.z > 0.f ? tt.z : 0.2f * tt.z;
      tt.w = tt.w > 0.f ? tt.w : 0.2f * tt.w;
      float pp = tt.x * at4.x + tt.y * at4.y + tt.z * at4.z + tt.w * at4.w;
#pragma unroll
      for (int d = 1; d < 16; d <<= 1) pp += __shfl_xor(pp, d);  // unit-level sum
      float mn = fmaxf(m, pp);
      float cf = __expf(m - mn);
      float w  = __expf(pp - mn);
      s = s * cf + w;
      o.x = o.x * cf + w * xlc.x;
      o.y = o.y * cf + w * xlc.y;
      o.z = o.z * cf + w * xlc.z;
      o.w = o.w * cf + w * xlc.w;
      m = mn;
    }
    xlc = xln;
  }
  float inv = (s > 0.f) ? 1.f / s : 0.f;
  f32x4 b4 = ld4(bias, fbf, c0);
  f32x4 val;
  val.x = o.x * inv + b4.x;
  val.y = o.y * inv + b4.y;
  val.z = o.z * inv + b4.z;
  val.w = o.w * inv + b4.w;
  st4(dout, fbf, PRE_OFF + (long long)i * F_DIM + c0, val);
}

// ---------------------------------------------------------------------------
// Pass 2 (pure streaming, x4): fc (at PRE_OFF) -> out_fc; leaky_relu -> out_pre.
// ---------------------------------------------------------------------------
__global__ __launch_bounds__(256) void post_k(void* __restrict__ dout,
                                              const int* __restrict__ flags) {
  int fbf = flags[2];
  long long idx = ((long long)blockIdx.x * 256 + threadIdx.x) * 4;
  if (idx >= NODE_ELEMS) return;
  f32x4 fc = ld4(dout, fbf, PRE_OFF + idx);
  st4(dout, fbf, FC_OFF + idx, fc);
  f32x4 pre;
  pre.x = fc.x > 0.f ? fc.x : 0.01f * fc.x;        // F.leaky_relu default slope
  pre.y = fc.y > 0.f ? fc.y : 0.01f * fc.y;
  pre.z = fc.z > 0.f ? fc.z : 0.01f * fc.z;
  pre.w = fc.w > 0.f ? fc.w : 0.01f * fc.w;
  st4(dout, fbf, PRE_OFF + idx, pre);
}

// ---------------------------------------------------------------------------
// Pooling: batch sorted -> register accumulation, flush on graph change.
// ---------------------------------------------------------------------------
__global__ __launch_bounds__(192) void pool_k(const void* __restrict__ dout,
                                              const int* __restrict__ batch,
                                              const int* __restrict__ flags,
                                              float* __restrict__ pool_sum) {
  int fbf = flags[2], is64b = flags[1];
  int t = threadIdx.x;                       // channel
  int r0 = blockIdx.x * POOL_ROWS;
  int rend = r0 + POOL_ROWS;
  if (rend > N_NODES) rend = N_NODES;
  if (r0 >= N_NODES) return;
  float acc = 0.f;
  int gcur = ld_idx(batch, is64b, r0);
  for (int r = r0; r < rend; ++r) {
    int g = ld_idx(batch, is64b, r);
    if (g != gcur) {
      if ((unsigned)gcur < (unsigned)NGRAPH)
        atomicAdd(&pool_sum[gcur * F_DIM + t], acc);
      acc = 0.f;
      gcur = g;
    }
    acc += ldf(dout, fbf, PRE_OFF + (long long)r * F_DIM + t);
  }
  if ((unsigned)gcur < (unsigned)NGRAPH)
    atomicAdd(&pool_sum[gcur * F_DIM + t], acc);
}

// ---------------------------------------------------------------------------
__global__ __launch_bounds__(192) void final_k(const float* __restrict__ pool_sum,
                                               const int* __restrict__ gbound,
                                               const void* __restrict__ Wc,
                                               const void* __restrict__ bc,
                                               void* __restrict__ dout,
                                               const int* __restrict__ flags) {
  __shared__ float sp[F_DIM];
  int fbf = flags[2];
  int g = blockIdx.x, t = threadIdx.x;
  int cn = gbound[g + 1] - gbound[g];
  if (cn < 1) cn = 1;
  float pv = pool_sum[g * F_DIM + t] / (float)cn;
  stf(dout, fbf, PP_OFF + (long long)g * F_DIM + t, pv);
  sp[t] = pv;
  __syncthreads();
  if (t < NCLS) {
    float a = ldf(bc, fbf, t);
#pragma unroll 4
    for (int cc = 0; cc < F_DIM; ++cc) a += sp[cc] * ldf(Wc, fbf, cc * NCLS + t);
    stf(dout, fbf, LOGITS_OFF + (long long)g * NCLS + t, a);
  }
}

// ---------------------------------------------------------------------------
extern "C" void kernel_launch(void* const* d_in, const int* in_sizes, int n_in,
                              void* d_out, int out_size, void* d_ws, size_t ws_size,
                              hipStream_t stream) {
  const void* x    = d_in[0];
  const int*  ei   = (const int*)d_in[1];
  const int*  bat  = (const int*)d_in[2];
  const void* Wl   = d_in[3];
  const void* bl   = d_in[4];
  const void* Wr   = d_in[5];
  const void* br   = d_in[6];
  const void* att  = d_in[7];
  const void* bias = d_in[8];
  const void* Wc   = d_in[9];
  const void* bc   = d_in[10];

  // workspace carve — total ~8.1 MB
  char* p = (char*)d_ws;
  auto carve = [&](size_t bytes) { char* r = p; p += (bytes + 511) & ~(size_t)511; return r; };
  int*   flags    = (int*)carve(3 * 4);
  int*   zbase    = (int*)carve((size_t)ZWORDS * 4);   // deg | pool_sum
  int*   deg      = zbase;
  float* pool_sum = (float*)(zbase + N_NODES);
  int* gbound   = (int*)carve((size_t)(NGRAPH + 1) * 4);
  int* row_ptr  = (int*)carve((size_t)(N_NODES + 1) * 4);
  int* cursor   = (int*)carve((size_t)N_NODES * 4);
  int* csum     = (int*)carve(128 * 4);
  int* edge_src = (int*)carve((size_t)E_TOT * 4);      // 6.8 MB
  // wt aliases edge_src: wt (384 KB) is consumed by gemm_mfma, which completes
  // (stream-ordered) before scan_c/fill_k write edge_src. No overlap hazard.
  unsigned short* wt = (unsigned short*)edge_src;

  AmazonNet_36704790511894_kernel<<<1, 64, 0, stream>>>();   // template symbol no-op
  detect_k<<<1, 256, 0, stream>>>(ei, bat, (const unsigned short*)x, flags);
  zero_k<<<(ZWORDS + 255) / 256, 256, 0, stream>>>(zbase, d_out, flags);

  // linear transforms via split-bf16 MFMA: xl -> FC_OFF, xr -> PRE_OFF
  wsplit_k<<<(WT_N + 255) / 256, 256, 0, stream>>>(Wl, Wr, flags, wt);
  gemm_mfma<<<MBLK, 256, 0, stream>>>(x, wt, bl, br, d_out, flags);

  // CSR by destination (real edges only; self-loops placed in scan_c)
  int eblk = (N_EDGES + 255) / 256;   // 6250
  hist_k<<<eblk, 256, 0, stream>>>(ei, bat, flags, deg, gbound);
  int nchunk = (N_NODES + 1023) / 1024;   // 98
  scan_a<<<nchunk, 256, 0, stream>>>(deg, csum);
  scan_b<<<1, 64, 0, stream>>>(csum, row_ptr, nchunk);
  scan_c<<<nchunk, 256, 0, stream>>>(deg, csum, row_ptr, cursor, edge_src);
  fill_k<<<eblk, 256, 0, stream>>>(ei, flags, cursor, edge_src);

  // attention: 300000 units, 4 per wave, 4 waves per block -> 18750 blocks
  attn1_k<<<N_UNITS_ATTN / 16, 256, 0, stream>>>(d_out, att, bias, row_ptr,
                                                 edge_src, flags);
  // finalize outputs (pure streaming), then register-accumulated pooling
  post_k<<<(int)((NODE_ELEMS / 4 + 255) / 256), 256, 0, stream>>>(d_out, flags);
  pool_k<<<(N_NODES + POOL_ROWS - 1) / POOL_ROWS, 192, 0, stream>>>(d_out, bat, flags, pool_sum);
  final_k<<<NGRAPH, F_DIM, 0, stream>>>(pool_sum, gbound, Wc, bc, d_out, flags);
}